// Round 1
// baseline (404.153 us; speedup 1.0000x reference)
//
#include <hip/hip_runtime.h>

#define NFFT    512
#define KOUT    256
#define SHIFT   160
#define NFRAMES 601
#define TLEN    96512
#define NBATCH  32
#define BFR     32      // frames per block
#define NCHUNK  16      // n (K-dim) chunk staged in LDS
#define EPSF    1e-7f

// out[b][k][f] = normalize_k( log10(sqrt(re^2+im^2+eps)) ),
//   re[b][k][f] = sum_n x[b][f*SHIFT+n] * Wr[k][n]   (k < 256 only)
__global__ __launch_bounds__(256) void dft_spec_kernel(
    const float* __restrict__ x,
    const float* __restrict__ Wr,
    const float* __restrict__ Wi,
    float* __restrict__ out)
{
    __shared__ float  Wr_s[KOUT * NCHUNK];     // [k][swz(n4)][4]  16 KB
    __shared__ float  Wi_s[KOUT * NCHUNK];     // 16 KB
    __shared__ float  Fr_s[BFR * NCHUNK];      // [f][swz(n4)][4]   2 KB
    __shared__ float2 red_s[32 * 32];          // [kgrp][f] partial (sum,sumsq) 8 KB
    __shared__ float  mean_s[BFR], rstd_s[BFR];

    const int tid    = threadIdx.x;
    const int b      = blockIdx.y;
    const int f_base = blockIdx.x * BFR;
    const int k_grp  = tid >> 3;        // 0..31 -> 8 k's each
    const int f_grp  = tid & 7;         // 0..7  -> 4 f's each
    const int k0     = k_grp * 8;

    const float* __restrict__ xb = x + b * TLEN;

    float accr[8][4] = {};
    float acci[8][4] = {};

    for (int nc = 0; nc < NFFT; nc += NCHUNK) {
        // ---- stage W tiles (256 x 16 each), float4, XOR-swizzled by (k>>3)&3 ----
        #pragma unroll
        for (int r = 0; r < 4; ++r) {
            const int q  = tid + 256 * r;       // 0..1023 float4 slots
            const int k  = q >> 2;
            const int n4 = q & 3;
            const int dst = k * NCHUNK + ((n4 ^ ((k >> 3) & 3)) << 2);
            const float4 vr = *(const float4*)(Wr + k * NFFT + nc + (n4 << 2));
            const float4 vi = *(const float4*)(Wi + k * NFFT + nc + (n4 << 2));
            *(float4*)(Wr_s + dst) = vr;
            *(float4*)(Wi_s + dst) = vi;
        }
        // ---- stage frame slice (32 x 16), XOR-swizzled by (f>>2)&3 ----
        if (tid < (BFR * NCHUNK / 4)) {
            const int f  = tid >> 2;
            const int n4 = tid & 3;
            const int fg = f_base + f;
            float4 v = make_float4(0.f, 0.f, 0.f, 0.f);
            if (fg < NFRAMES)
                v = *(const float4*)(xb + fg * SHIFT + nc + (n4 << 2));
            *(float4*)(Fr_s + f * NCHUNK + ((n4 ^ ((f >> 2) & 3)) << 2)) = v;
        }
        __syncthreads();

        // ---- 1024 FMAs per thread per chunk ----
        #pragma unroll
        for (int n4 = 0; n4 < 4; ++n4) {
            float4 fv[4];
            #pragma unroll
            for (int j = 0; j < 4; ++j)
                fv[j] = *(const float4*)(Fr_s + (f_grp * 4 + j) * NCHUNK
                                         + ((n4 ^ (f_grp & 3)) << 2));
            #pragma unroll
            for (int i = 0; i < 8; ++i) {
                const int swz = ((n4 ^ (k_grp & 3)) << 2);
                const float4 wr = *(const float4*)(Wr_s + (k0 + i) * NCHUNK + swz);
                const float4 wi = *(const float4*)(Wi_s + (k0 + i) * NCHUNK + swz);
                #pragma unroll
                for (int j = 0; j < 4; ++j) {
                    accr[i][j] += wr.x * fv[j].x + wr.y * fv[j].y
                                + wr.z * fv[j].z + wr.w * fv[j].w;
                    acci[i][j] += wi.x * fv[j].x + wi.y * fv[j].y
                                + wi.z * fv[j].z + wi.w * fv[j].w;
                }
            }
        }
        __syncthreads();
    }

    // ---- log-magnitude:  0.5*log10(re^2+im^2+eps) = 0.5*log10(2)*log2(z) ----
    const float C = 0.15051499783199057f;   // 0.5 * log10(2)
    float v[8][4];
    float s1[4] = {}, s2[4] = {};
    #pragma unroll
    for (int i = 0; i < 8; ++i)
        #pragma unroll
        for (int j = 0; j < 4; ++j) {
            const float z  = accr[i][j] * accr[i][j] + acci[i][j] * acci[i][j] + EPSF;
            const float lv = C * __log2f(z);
            v[i][j] = lv;
            s1[j] += lv;
            s2[j] += lv * lv;
        }

    // ---- block reduction over k (256 values per (b,f) column) ----
    #pragma unroll
    for (int j = 0; j < 4; ++j)
        red_s[k_grp * 32 + f_grp * 4 + j] = make_float2(s1[j], s2[j]);
    __syncthreads();

    if (tid < BFR) {
        float a = 0.f, q = 0.f;
        #pragma unroll 8
        for (int kg = 0; kg < 32; ++kg) {
            const float2 p = red_s[kg * 32 + tid];
            a += p.x;
            q += p.y;
        }
        const float mean = a * (1.f / 256.f);
        float var = q * (1.f / 256.f) - mean * mean;
        var = fmaxf(var, 0.f);
        mean_s[tid] = mean;
        rstd_s[tid] = 1.f / (__builtin_sqrtf(var) + EPSF);
    }
    __syncthreads();

    // ---- normalize + store ----
    #pragma unroll
    for (int j = 0; j < 4; ++j) {
        const int fl = f_grp * 4 + j;
        const int fg = f_base + fl;
        if (fg < NFRAMES) {
            const float mean = mean_s[fl];
            const float rs   = rstd_s[fl];
            #pragma unroll
            for (int i = 0; i < 8; ++i)
                out[(b * KOUT + k0 + i) * NFRAMES + fg] = (v[i][j] - mean) * rs;
        }
    }
}

extern "C" void kernel_launch(void* const* d_in, const int* in_sizes, int n_in,
                              void* d_out, int out_size, void* d_ws, size_t ws_size,
                              hipStream_t stream) {
    const float* x  = (const float*)d_in[0];
    const float* Wr = (const float*)d_in[1];
    const float* Wi = (const float*)d_in[2];
    float* out = (float*)d_out;

    dim3 grid((NFRAMES + BFR - 1) / BFR, NBATCH);
    dft_spec_kernel<<<grid, 256, 0, stream>>>(x, Wr, Wi, out);
}

// Round 2
// 61.753 us; speedup vs baseline: 6.5446x; 6.5446x over previous
//
#include <hip/hip_runtime.h>
#include <stdint.h>

#define TLEN    96512
#define NBATCH  32
#define NFFT    512
#define KOUT    256
#define SHIFT   160
#define NFRAMES 601
#define FT      64            // f-tile per block
#define NK      32            // K-steps (512/16)
#define BK      16
#define EPSF    1e-7f

typedef _Float16 f16;
typedef _Float16 half8 __attribute__((ext_vector_type(8)));
typedef float f32x16 __attribute__((ext_vector_type(16)));

// ---------------- workspace layout ----------------
// [0, 1MB):  W chunks: [ks][k][slot'] of 16B units; slot = (ri*2+hl)*2 + s,
//            slot' = slot ^ (k&7)  (pre-swizzled for conflict-free ds_read_b128)
// [1MB, ..): x split planes: [b][hl][t] halves
#define WS_W_HALVES (NK * 256 * 64)       // 524288 halves = 1 MB
#define WS_W_BYTES  (WS_W_HALVES * 2)

// ---------------- LDS layout (GEMM) ----------------
#define LDS_W_OFF    0
#define LDS_W_BYTES  32768                 // one BK=16 chunk: 256k x 128B rows
#define XSEG_PLANE   21504                 // bytes per hi/lo plane (1344 x 16B units)
#define LDS_X_OFF    LDS_W_BYTES
#define LDS_RED_OFF  (LDS_W_BYTES + 2*XSEG_PLANE)   // 75776
#define LDS_STAT_OFF (LDS_RED_OFF + 2048)           // 77824
#define LDS_TOTAL    (LDS_STAT_OFF + 512)           // 78336

// ============ split W into f16 hi/lo, pre-chunked + pre-swizzled ============
__global__ __launch_bounds__(256) void split_w_kernel(
    const float* __restrict__ Wr, const float* __restrict__ Wi,
    f16* __restrict__ wsW)
{
    int id   = blockIdx.x * 256 + threadIdx.x;   // 65536 = 32ks * 256k * 8slots
    int ks   = id >> 11;
    int k    = (id >> 3) & 255;
    int slot = id & 7;
    int p  = slot >> 1, s = slot & 1;            // plane p = ri*2+hl
    int ri = p >> 1, hl = p & 1;
    const float* src = (ri ? Wi : Wr) + k * NFFT + ks * BK + s * 8;
    f16 vals[8];
    #pragma unroll
    for (int j = 0; j < 8; ++j) {
        float v = src[j];
        f16 h = (f16)v;
        f16 l = (f16)(v - (float)h);
        vals[j] = hl ? l : h;
    }
    int slotp = slot ^ (k & 7);
    *(half8*)(wsW + ((size_t)ks * 2048 + k * 8 + slotp) * 8) = *(half8*)vals;
}

// ============ split x into f16 hi/lo planes ============
__global__ __launch_bounds__(256) void split_x_kernel(
    const float* __restrict__ x, f16* __restrict__ wsX)
{
    const int nt8 = TLEN / 8;                    // 12064
    int id = blockIdx.x * 256 + threadIdx.x;
    if (id >= NBATCH * nt8) return;
    int b = id / nt8, t8 = id % nt8;
    const float* src = x + (size_t)b * TLEN + t8 * 8;
    f16 h[8], l[8];
    #pragma unroll
    for (int j = 0; j < 8; ++j) {
        float v = src[j];
        h[j] = (f16)v;
        l[j] = (f16)(v - (float)h[j]);
    }
    size_t base = (size_t)(b * 2) * TLEN + t8 * 8;
    *(half8*)(wsX + base)        = *(half8*)h;
    *(half8*)(wsX + base + TLEN) = *(half8*)l;
}

// ============ async global->LDS 16B ============
typedef const __attribute__((address_space(1))) uint32_t g_u32;
typedef __attribute__((address_space(3))) uint32_t      l_u32;

__device__ inline void stage_w_chunk(const f16* __restrict__ wsW, char* smem,
                                     int ks, int w, int lane)
{
    const f16* g = wsW + (size_t)ks * (256 * 64);      // 32KB chunk
    #pragma unroll
    for (int it = 0; it < 8; ++it) {
        int chunk = it * 4 + w;                        // 32 x 1KB wave-chunks
        const f16* gp = g + chunk * 512 + lane * 8;
        char* lp = smem + LDS_W_OFF + chunk * 1024;    // + lane*16 implied by HW
        __builtin_amdgcn_global_load_lds((g_u32*)gp, (l_u32*)lp, 16, 0, 0);
    }
}

// ============ main MFMA kernel ============
__global__ __launch_bounds__(256, 2) void dft_mfma_kernel(
    const f16* __restrict__ wsW, const f16* __restrict__ wsX,
    float* __restrict__ out)
{
    __shared__ uint4 smem4[LDS_TOTAL / 16];
    char* smem = (char*)smem4;

    const int tid  = threadIdx.x;
    const int lane = tid & 63;
    const int w    = tid >> 6;         // wave 0..3, stacked along k
    const int l31  = lane & 31;
    const int lhi  = lane >> 5;
    const int b    = blockIdx.y;
    const int f0   = blockIdx.x * FT;
    const int kb   = w * 64;

    // ---- issue W chunk 0 (async), then stage x segment ----
    stage_w_chunk(wsW, smem, 0, w, lane);
    {
        const int units = XSEG_PLANE / 16;             // 1344
        #pragma unroll
        for (int hl = 0; hl < 2; ++hl) {
            const f16* src = wsX + ((size_t)b * 2 + hl) * TLEN;
            for (int u = tid; u < units; u += 256) {
                int s0 = f0 * SHIFT + u * 8;
                half8 v = {};
                if (s0 + 8 <= TLEN) {
                    v = *(const half8*)(src + s0);
                } else {
                    #pragma unroll
                    for (int j = 0; j < 8; ++j)
                        ((f16*)&v)[j] = (s0 + j < TLEN) ? src[s0 + j] : (f16)0.f;
                }
                int up = u ^ ((u >> 3) & 7);           // 16B-unit XOR swizzle
                *(half8*)(smem + LDS_X_OFF + hl * XSEG_PLANE + up * 16) = v;
            }
        }
    }
    __syncthreads();   // drains vmcnt (W0 landed) + lgkm (x staged)

    f32x16 acc[2][2][2] = {};   // [m][nf][ri]

    const int arow0 = kb + l31;
    const int bu0   = l31 * 20 + lhi;          // x-seg 16B-unit base, nf=0
    const int bu1   = (32 + l31) * 20 + lhi;   // nf=1

    for (int ks = 0; ks < NK; ++ks) {
        half8 a[2][2][2], bb[2][2];
        #pragma unroll
        for (int m = 0; m < 2; ++m) {
            int k = arow0 + m * 32;
            #pragma unroll
            for (int ri = 0; ri < 2; ++ri)
                #pragma unroll
                for (int hl = 0; hl < 2; ++hl) {
                    int slot = ((((ri << 1) | hl) << 1) | lhi) ^ (k & 7);
                    a[m][ri][hl] = *(const half8*)(smem + LDS_W_OFF + k * 128 + slot * 16);
                }
        }
        #pragma unroll
        for (int nf = 0; nf < 2; ++nf) {
            int u = (nf ? bu1 : bu0) + ks * 2;
            int up = u ^ ((u >> 3) & 7);
            #pragma unroll
            for (int hl = 0; hl < 2; ++hl)
                bb[nf][hl] = *(const half8*)(smem + LDS_X_OFF + hl * XSEG_PLANE + up * 16);
        }
        __syncthreads();                       // all waves done reading W chunk ks
        if (ks + 1 < NK) stage_w_chunk(wsW, smem, ks + 1, w, lane);

        #pragma unroll
        for (int m = 0; m < 2; ++m)
            #pragma unroll
            for (int nf = 0; nf < 2; ++nf)
                #pragma unroll
                for (int ri = 0; ri < 2; ++ri) {
                    acc[m][nf][ri] = __builtin_amdgcn_mfma_f32_32x32x16_f16(
                        a[m][ri][0], bb[nf][0], acc[m][nf][ri], 0, 0, 0);
                    acc[m][nf][ri] = __builtin_amdgcn_mfma_f32_32x32x16_f16(
                        a[m][ri][0], bb[nf][1], acc[m][nf][ri], 0, 0, 0);
                    acc[m][nf][ri] = __builtin_amdgcn_mfma_f32_32x32x16_f16(
                        a[m][ri][1], bb[nf][0], acc[m][nf][ri], 0, 0, 0);
                }
        __syncthreads();                       // chunk ks+1 landed (vmcnt drained)
    }

    // ---- epilogue: log-magnitude + per-(b,f) mean/std over k ----
    const float C = 0.15051499783199057f;      // 0.5*log10(2)
    float lg[2][2][16];
    float s1[2] = {0.f, 0.f}, s2[2] = {0.f, 0.f};
    #pragma unroll
    for (int m = 0; m < 2; ++m)
        #pragma unroll
        for (int nf = 0; nf < 2; ++nf)
            #pragma unroll
            for (int r = 0; r < 16; ++r) {
                float re = acc[m][nf][0][r], im = acc[m][nf][1][r];
                float lv = C * __log2f(re * re + im * im + EPSF);
                lg[m][nf][r] = lv;
                s1[nf] += lv;
                s2[nf] += lv * lv;
            }
    #pragma unroll
    for (int nf = 0; nf < 2; ++nf) {           // fold lanes l <-> l+32 (same f col)
        s1[nf] += __shfl_xor(s1[nf], 32);
        s2[nf] += __shfl_xor(s2[nf], 32);
    }
    float2* red = (float2*)(smem + LDS_RED_OFF);
    if (lane < 32) {
        red[(w * 2 + 0) * 32 + l31] = make_float2(s1[0], s2[0]);
        red[(w * 2 + 1) * 32 + l31] = make_float2(s1[1], s2[1]);
    }
    __syncthreads();
    float* stat = (float*)(smem + LDS_STAT_OFF);   // mean[64], rstd[64]
    if (tid < 64) {
        float S1 = 0.f, S2 = 0.f;
        int nf = tid >> 5, c = tid & 31;
        #pragma unroll
        for (int ww = 0; ww < 4; ++ww) {
            float2 p = red[(ww * 2 + nf) * 32 + c];
            S1 += p.x; S2 += p.y;
        }
        float mean = S1 * (1.f / 256.f);
        float var  = fmaxf(S2 * (1.f / 256.f) - mean * mean, 0.f);
        stat[tid]      = mean;
        stat[64 + tid] = 1.f / (__builtin_sqrtf(var) + EPSF);
    }
    __syncthreads();

    #pragma unroll
    for (int nf = 0; nf < 2; ++nf) {
        int fl = nf * 32 + l31;
        int f  = f0 + fl;
        if (f >= NFRAMES) continue;
        float mean = stat[fl], rstd = stat[64 + fl];
        #pragma unroll
        for (int m = 0; m < 2; ++m)
            #pragma unroll
            for (int r = 0; r < 16; ++r) {
                int k = kb + m * 32 + (r & 3) + ((r >> 2) << 3) + (lhi << 2);
                out[((size_t)b * KOUT + k) * NFRAMES + f] = (lg[m][nf][r] - mean) * rstd;
            }
    }
}

extern "C" void kernel_launch(void* const* d_in, const int* in_sizes, int n_in,
                              void* d_out, int out_size, void* d_ws, size_t ws_size,
                              hipStream_t stream) {
    const float* x  = (const float*)d_in[0];
    const float* Wr = (const float*)d_in[1];
    const float* Wi = (const float*)d_in[2];
    float* out = (float*)d_out;

    f16* wsW = (f16*)d_ws;
    f16* wsX = (f16*)((char*)d_ws + WS_W_BYTES);

    split_w_kernel<<<256, 256, 0, stream>>>(Wr, Wi, wsW);
    const int nt8 = TLEN / 8;
    split_x_kernel<<<(NBATCH * nt8 + 255) / 256, 256, 0, stream>>>(x, wsX);

    dim3 grid((NFRAMES + FT - 1) / FT, NBATCH);   // 10 x 32
    dft_mfma_kernel<<<grid, 256, 0, stream>>>(wsW, wsX, out);
}